// Round 10
// baseline (420.685 us; speedup 1.0000x reference)
//
#include <hip/hip_runtime.h>
#include <stdint.h>

// ---------------------------------------------------------------------------
// LlamaAttention forward, MI355X (gfx950), input-dtype-agnostic (bf16 or fp32)
//   x:(2,2048,2048) Wq/Wk/Wv/Wo:(2048,2048)  out:(2,2048,2048)
// R15: attn double-buffer rebuilt on the guide's VERIFIED minimum 2-phase
//   recipe (T3): per iter { stage(t+1) -> buf^1 FIRST; compute buf[t&1];
//   vmcnt(0); barrier }. One drain+barrier per tile, issued-before-compute
//   so the next tile's HBM latency hides under this tile's compute.
//   R13/R14's counted-vmcnt(8) 3-deep ledger abandoned after two numeric
//   failures (PV read unwritten LDS -> garbage V -> absmax 7e32; s_barrier
//   carries no compiler memory semantics, reads can cross it; sched_barrier
//   placed after each barrier blocks that here).
//   gemm256 byte-identical to thrice-passed R10 schedule (126-127 us).
// Workspace (u16 units, SLOT = 2048*2048 = 4194304):
//   0..1 xb (fp32 path only) | 2..4 WqT WkT WvT (contiguous) | 5 WoT
//   6..7 Q(=Ab) | 8..9 K | 10..11 V | flag at 12*SLOT.  ~96 MB.
//   V^T staged in d_out (dead before final GEMM).
// ---------------------------------------------------------------------------

typedef unsigned short u16;
typedef __attribute__((ext_vector_type(8))) short bf16x8;   // 8 bf16 = 4 VGPRs
typedef __attribute__((ext_vector_type(4))) float f32x4;    // MFMA C/D frag
typedef __attribute__((ext_vector_type(2))) unsigned int u32x2;

__device__ __forceinline__ u16 f2bf(float f) {
  union { float f; uint32_t u; } v; v.f = f;
  return (u16)((v.u + 0x7fffu + ((v.u >> 16) & 1u)) >> 16);  // RNE
}

__device__ __forceinline__ float fast_exp2(float x) {
#if __has_builtin(__builtin_amdgcn_exp2f)
  return __builtin_amdgcn_exp2f(x);
#else
  return exp2f(x);
#endif
}

// async global->LDS, 16 B per lane; lds base must be wave-uniform (m97/m104)
__device__ __forceinline__ void gl_lds16(const void* g, void* l) {
  __builtin_amdgcn_global_load_lds(
      (const __attribute__((address_space(1))) unsigned int*)g,
      (__attribute__((address_space(3))) unsigned int*)l, 16, 0, 0);
}

// ---- dtype sniffer --------------------------------------------------------
__global__ __launch_bounds__(256) void sniff_k(const u16* __restrict__ x,
                                               int* __restrict__ flag) {
  __shared__ int cnt;
  const int t = threadIdx.x;
  if (t == 0) cnt = 0;
  __syncthreads();
  int sane = 0;
#pragma unroll
  for (int i = 0; i < 16; ++i) {
    u16 u = x[t * 16 + i];
    int e = (u >> 7) & 0xff;
    sane += (e >= 90 && e <= 150) ? 1 : 0;
  }
  atomicAdd(&cnt, sane);
  __syncthreads();
  if (t == 0) *flag = (cnt >= 3700) ? 0 : 1;  // 0 = bf16, 1 = fp32
}

// ---- x conversion (fp32 path only; bf16 path early-outs) ------------------
__global__ __launch_bounds__(256) void convert_x_k(const void* __restrict__ xin,
                                                   u16* __restrict__ xb,
                                                   const int* __restrict__ flag) {
  if (*flag == 0) return;  // bf16: GEMM reads x directly
  const int i = (blockIdx.x * 256 + threadIdx.x) * 8;
  const float* xf = (const float*)xin;
  float4 a = *(const float4*)(xf + i);
  float4 b = *(const float4*)(xf + i + 4);
  bf16x8 o;
  o[0] = (short)f2bf(a.x); o[1] = (short)f2bf(a.y);
  o[2] = (short)f2bf(a.z); o[3] = (short)f2bf(a.w);
  o[4] = (short)f2bf(b.x); o[5] = (short)f2bf(b.y);
  o[6] = (short)f2bf(b.z); o[7] = (short)f2bf(b.w);
  *(bf16x8*)(xb + i) = o;
}

// ---- weight convert + transpose, all 4 weights: grid (32,32,4) ------------
__global__ __launch_bounds__(256) void convert_transpose_k(const void* __restrict__ w0,
                                                           const void* __restrict__ w1,
                                                           const void* __restrict__ w2,
                                                           const void* __restrict__ w3,
                                                           u16* __restrict__ out_base,
                                                           const int* __restrict__ flag) {
  __shared__ u16 tile[64][66];
  const int z = blockIdx.z;
  const void* in = (z == 0) ? w0 : (z == 1) ? w1 : (z == 2) ? w2 : w3;
  u16* out = out_base + (size_t)z * 4194304u;
  const int tr = blockIdx.y, tc = blockIdx.x, t = threadIdx.x;
  if (*flag) {
    const float* inf32 = (const float*)in;
#pragma unroll
    for (int i = 0; i < 16; ++i) {
      int idx = t + i * 256, r = idx >> 6, c = idx & 63;
      tile[r][c] = f2bf(inf32[(size_t)(tr * 64 + r) * 2048 + tc * 64 + c]);
    }
  } else {
    const u16* inb = (const u16*)in;
#pragma unroll
    for (int i = 0; i < 16; ++i) {
      int idx = t + i * 256, r = idx >> 6, c = idx & 63;
      tile[r][c] = inb[(size_t)(tr * 64 + r) * 2048 + tc * 64 + c];
    }
  }
  __syncthreads();
#pragma unroll
  for (int i = 0; i < 16; ++i) {
    int idx = t + i * 256, r = idx >> 6, c = idx & 63;
    out[(size_t)(tc * 64 + r) * 2048 + tr * 64 + c] = tile[c][r];
  }
}

// ---- bf16 transpose (V -> V^T per batch), grid (32,32,2) ------------------
__global__ __launch_bounds__(256) void transpose_k(const u16* __restrict__ in,
                                                   u16* __restrict__ out) {
  __shared__ u16 tile[64][66];
  const size_t zoff = (size_t)blockIdx.z * 4194304u;
  in += zoff; out += zoff;
  const int tr = blockIdx.y, tc = blockIdx.x, t = threadIdx.x;
#pragma unroll
  for (int i = 0; i < 16; ++i) {
    int idx = t + i * 256, r = idx >> 6, c = idx & 63;
    tile[r][c] = in[(size_t)(tr * 64 + r) * 2048 + tc * 64 + c];
  }
  __syncthreads();
#pragma unroll
  for (int i = 0; i < 16; ++i) {
    int idx = t + i * 256, r = idx >> 6, c = idx & 63;
    out[(size_t)(tc * 64 + r) * 2048 + tr * 64 + c] = tile[c][r];
  }
}

// ---- 256x256 8-phase GEMM: C = A[4096,2048] x Bt[6144,2048]^T -------------
// R10 schedule (measured 126-127 us, passed 3x). 512 thr = 8 waves. Per phase
// ALL waves compute one 128x128 C-quadrant (mh,nh). Phase reads only A-half
// mh + B-half nh. LDS: Ls[buf][A/B][half][128*64] u16 = 128 KiB.
// Stage schedule (2 gl_lds per half per thread):
//   ph1: u1.HA1+HB1 | ph3: u2.HA0 | ph4: u2.HB0 +vmcnt(4)
//   ph5: u2.HA1+HB1 | ph7: u3.HA0 | ph8: u3.HB0 +vmcnt(4)
__global__ __launch_bounds__(512, 2) void gemm256(const u16* __restrict__ A,
                                                  const void* __restrict__ Araw,
                                                  const int* __restrict__ aflag,
                                                  const u16* __restrict__ Bt,
                                                  u16* __restrict__ Cbase,
                                                  float qscale) {
  __shared__ __align__(16) u16 Ls[2][2][2][128 * 64];  // [buf][A/B][half]

  const int t = threadIdx.x, wave = t >> 6, lane = t & 63;
  const int g = lane >> 4, lq = lane & 15;
  const int wr = wave >> 2, wc = wave & 3;   // 2 x 4 wave grid
  // bijective XCD swizzle (nwg = 384, 384 % 8 == 0)
  const int bid = blockIdx.x;
  const int swz = (bid & 7) * 48 + (bid >> 3);
  const int bm = swz / 24, bn = swz % 24;

  const u16* Ause = (*aflag == 0) ? (const u16*)Araw : A;
  const u16* Arow = Ause + (size_t)(bm * 256) * 2048;
  const u16* Brow = Bt + (size_t)(bn * 256) * 2048;
  const int lr = lane >> 3, lcs = ((lane & 7) ^ lr) * 8;

  int cofs[2];
#pragma unroll
  for (int kk = 0; kk < 2; ++kk) cofs[kk] = ((kk * 4 + g) ^ (lq & 7)) * 8;

  f32x4 acc[8][4];   // [mh*4+m][nh*2+n]
#pragma unroll
  for (int i = 0; i < 8; ++i)
#pragma unroll
    for (int j = 0; j < 4; ++j) acc[i][j] = f32x4{0.f, 0.f, 0.f, 0.f};

  // stage one half-tile (mat: 0=A 1=B, half h) of K-tile tt into buf tt&1
  auto stageH = [&](int tt, int mat, int h) {
    const u16* src = mat ? Brow : Arow;
    u16* dst = &Ls[tt & 1][mat][h][0];
    const int kb = tt * 64;
#pragma unroll
    for (int i = 0; i < 2; ++i) {
      const int s = wave * 2 + i;    // stripe of 8 rows within the half
      gl_lds16(src + (size_t)(h * 128 + s * 8 + lr) * 2048 + kb + lcs,
               dst + s * 8 * 64);
    }
  };

  bf16x8 af[8], bfr[4];
  auto ldA = [&](const u16* base) {   // base = &Ls[buf][0][mh][0]
#pragma unroll
    for (int m = 0; m < 4; ++m)
#pragma unroll
      for (int kk = 0; kk < 2; ++kk)
        af[m * 2 + kk] = *(const bf16x8*)(&base[(wr * 64 + m * 16 + lq) * 64 + cofs[kk]]);
  };
  auto ldB = [&](const u16* base) {   // base = &Ls[buf][1][nh][0]
#pragma unroll
    for (int n = 0; n < 2; ++n)
#pragma unroll
      for (int kk = 0; kk < 2; ++kk)
        bfr[n * 2 + kk] = *(const bf16x8*)(&base[(wc * 32 + n * 16 + lq) * 64 + cofs[kk]]);
  };
  auto mmac = [&](int mh, int nh) {
    __builtin_amdgcn_s_barrier();
    asm volatile("s_waitcnt lgkmcnt(0)" ::: "memory");
    __builtin_amdgcn_sched_barrier(0);
    __builtin_amdgcn_s_setprio(1);
#pragma unroll
    for (int m = 0; m < 4; ++m)
#pragma unroll
      for (int n = 0; n < 2; ++n)
#pragma unroll
        for (int kk = 0; kk < 2; ++kk)
          acc[mh * 4 + m][nh * 2 + n] = __builtin_amdgcn_mfma_f32_16x16x32_bf16(
              af[m * 2 + kk], bfr[n * 2 + kk], acc[mh * 4 + m][nh * 2 + n], 0, 0, 0);
    __builtin_amdgcn_s_setprio(0);
    __builtin_amdgcn_s_barrier();
  };

  // ---- prologue: tile0 complete + tile1.{HA0,HB0}; retire tile0 ----
  stageH(0, 0, 0); stageH(0, 1, 0); stageH(0, 0, 1); stageH(0, 1, 1);
  stageH(1, 0, 0); stageH(1, 1, 0);
  asm volatile("s_waitcnt vmcnt(4)" ::: "memory");
  __builtin_amdgcn_sched_barrier(0);
  __builtin_amdgcn_s_barrier();

  for (int it = 0; it < 16; ++it) {
    const int u1 = 2 * it + 1, u2 = 2 * it + 2, u3 = 2 * it + 3;
    // ph1: Q(0,0) buf0 | stage u1.HA1 + u1.HB1 (buf1 regions released ph8)
    ldA(&Ls[0][0][0][0]);
    ldB(&Ls[0][1][0][0]);
    stageH(u1, 0, 1); stageH(u1, 1, 1);
    mmac(0, 0);
    // ph2: Q(0,1) buf0 (af reused)
    ldB(&Ls[0][1][1][0]);
    mmac(0, 1);
    // ph3: Q(1,0) buf0 | stage u2.HA0 (buf0.HA0 released ph2)
    ldA(&Ls[0][0][1][0]);
    ldB(&Ls[0][1][0][0]);
    if (u2 < 32) stageH(u2, 0, 0);
    mmac(1, 0);
    // ph4: Q(1,1) buf0 | stage u2.HB0 (released ph3) | vmcnt: publish u1
    ldB(&Ls[0][1][1][0]);
    if (u2 < 32) stageH(u2, 1, 0);
    if (it < 15) asm volatile("s_waitcnt vmcnt(4)" ::: "memory");
    else         asm volatile("s_waitcnt vmcnt(0)" ::: "memory");
    __builtin_amdgcn_sched_barrier(0);
    mmac(1, 1);
    // ph5: Q(0,0) buf1 | stage u2.HA1 + u2.HB1 (buf0 halves released ph4)
    ldA(&Ls[1][0][0][0]);
    ldB(&Ls[1][1][0][0]);
    if (u2 < 32) { stageH(u2, 0, 1); stageH(u2, 1, 1); }
    mmac(0, 0);
    // ph6: Q(0,1) buf1
    ldB(&Ls[1][1][1][0]);
    mmac(0, 1);
    // ph7: Q(1,0) buf1 | stage u3.HA0 (buf1.HA0 released ph6)
    ldA(&Ls[1][0][1][0]);
    ldB(&Ls[1][1][0][0]);
    if (u3 < 32) stageH(u3, 0, 0);
    mmac(1, 0);
    // ph8: Q(1,1) buf1 | stage u3.HB0 (released ph7) | vmcnt: publish u2
    ldB(&Ls[1][1][1][0]);
    if (u3 < 32) stageH(u3, 1, 0);
    asm volatile("s_waitcnt vmcnt(4)" ::: "memory");   // no-op on last iter
    __builtin_amdgcn_sched_barrier(0);
    mmac(1, 1);
  }

  // ---- epilogue: C/D layout col = lane&15, row = (lane>>4)*4 + reg ----
  const int which = bn >> 3;  // 0=Q, 1=K, 2=V (each [4096][2048], contiguous)
  u16* C = Cbase + (size_t)which * 2u * 4194304u;
  const float scale = (which == 0) ? qscale : 1.0f;
  const int colbase = (bn & 7) * 256;
#pragma unroll
  for (int mh = 0; mh < 2; ++mh)
#pragma unroll
    for (int m = 0; m < 4; ++m)
#pragma unroll
      for (int nh = 0; nh < 2; ++nh)
#pragma unroll
        for (int n = 0; n < 2; ++n)
#pragma unroll
          for (int j = 0; j < 4; ++j) {
            size_t row = (size_t)(bm * 256 + mh * 128 + wr * 64 + m * 16 + g * 4 + j);
            size_t col = (size_t)(colbase + nh * 128 + wc * 32 + n * 16 + lq);
            C[row * 2048 + col] = f2bf(acc[mh * 4 + m][nh * 2 + n][j] * scale);
          }
}

// ---- C = A[4096,2048] x Bt[*,2048]^T, 128^2 (kept for output GEMM) --------
__global__ __launch_bounds__(256) void gemm_bt(const u16* __restrict__ A,
                                               const void* __restrict__ Araw,
                                               const int* __restrict__ aflag,
                                               const u16* __restrict__ Bt,
                                               u16* __restrict__ C0,
                                               u16* __restrict__ C1,
                                               u16* __restrict__ C2,
                                               float qscale,
                                               const int* __restrict__ outflag) {
  __shared__ u16 As[128 * 64];
  __shared__ u16 Bs[128 * 64];
  const int bx = blockIdx.x, by = blockIdx.y, t = threadIdx.x;
  const int wave = t >> 6, lane = t & 63;
  const int g = lane >> 4, lq = lane & 15;
  const int wr = wave >> 1, wc = wave & 1;
  const int which = bx >> 4, nb = bx & 15;
  u16* C = (which == 0) ? C0 : ((which == 1) ? C1 : C2);
  const float scale = (which == 0) ? qscale : 1.0f;
  const u16* Ause = (aflag && *aflag == 0) ? (const u16*)Araw : A;
  const int lr = lane >> 3, lcs = ((lane & 7) ^ lr) * 8;

  const u16* Arow = Ause + (size_t)(by * 128) * 2048;
  const u16* Brow = Bt + (size_t)(bx * 128) * 2048;

  int cofs[2];
#pragma unroll
  for (int ks = 0; ks < 2; ++ks) cofs[ks] = ((ks * 4 + g) ^ (lq & 7)) * 8;

  f32x4 acc[4][4];
#pragma unroll
  for (int i = 0; i < 4; ++i)
#pragma unroll
    for (int j = 0; j < 4; ++j) acc[i][j] = f32x4{0.f, 0.f, 0.f, 0.f};

  for (int kb = 0; kb < 2048; kb += 64) {
    __syncthreads();
#pragma unroll
    for (int i = 0; i < 4; ++i) {
      const int r = wave * 32 + i * 8;  // wave-uniform LDS base row
      gl_lds16(Arow + (size_t)(r + lr) * 2048 + kb + lcs, &As[r * 64]);
      gl_lds16(Brow + (size_t)(r + lr) * 2048 + kb + lcs, &Bs[r * 64]);
    }
    __syncthreads();
#pragma unroll
    for (int ks = 0; ks < 2; ++ks) {
      bf16x8 af[4], bfr[4];
#pragma unroll
      for (int mt = 0; mt < 4; ++mt)
        af[mt] = *(const bf16x8*)(&As[(wr * 64 + mt * 16 + lq) * 64 + cofs[ks]]);
#pragma unroll
      for (int nt = 0; nt < 4; ++nt)
        bfr[nt] = *(const bf16x8*)(&Bs[(wc * 64 + nt * 16 + lq) * 64 + cofs[ks]]);
#pragma unroll
      for (int mt = 0; mt < 4; ++mt)
#pragma unroll
        for (int nt = 0; nt < 4; ++nt)
          acc[mt][nt] = __builtin_amdgcn_mfma_f32_16x16x32_bf16(af[mt], bfr[nt], acc[mt][nt], 0, 0, 0);
    }
  }
  const int outF32 = outflag ? *outflag : 0;
#pragma unroll
  for (int mt = 0; mt < 4; ++mt)
#pragma unroll
    for (int nt = 0; nt < 4; ++nt)
#pragma unroll
      for (int j = 0; j < 4; ++j) {
        size_t row = (size_t)(by * 128 + wr * 64 + mt * 16 + g * 4 + j);
        size_t col = (size_t)(nb * 128 + wc * 64 + nt * 16 + lq);
        float v = acc[mt][nt][j] * scale;
        if (outF32) ((float*)C)[row * 2048 + col] = v;
        else C[row * 2048 + col] = f2bf(v);
      }
}

// ---- flash attention, fixed-shift softmax, register-resident P ------------
// R15: guide-verified minimum 2-phase double-buffer (T3 recipe):
//   prologue: stage(0); vmcnt(0); barrier.
//   iter tt:  stage(tt+1) -> buf^1 (free since last barrier; can't hoist
//             above it: SB(0) follows each barrier; can't sink below the
//             end vmcnt(0): asm memory clobber);
//             compute buf[tt&1]; vmcnt(0); barrier; SB(0).
//   Publication: stage drained by end-of-iter vmcnt(0) + barrier. WAR:
//   buf^1's readers finished before the previous barrier. HBM latency of
//   tile tt+1 hides under tile tt's QK^T+softmax+PV.
//   LDS 64 KiB -> 2 blk/CU; grid 1024 = 2 exact dispatch rounds.
__global__ __launch_bounds__(256, 2) void attn_kernel(const u16* __restrict__ Q,
                                                      const u16* __restrict__ K,
                                                      const u16* __restrict__ Vt,
                                                      u16* __restrict__ O) {
  __shared__ u16 Ks[2][64 * 128];  // chunk (row,c): row*128 + ((c ^ (row&7))*8)
  __shared__ u16 Vs[2][128 * 64];  // chunk (row,c): row*64  + ((c ^ (row&7))*8)

  const int qb = blockIdx.x, h = blockIdx.y, b = blockIdx.z;
  const int t = threadIdx.x, wave = t >> 6, lane = t & 63;
  const int g = lane >> 4, lq = lane & 15;

  const size_t qk_base = ((size_t)b * 2048) * 2048 + (size_t)h * 128;  // [b][s][h*128+dh]
  const size_t vt_base = ((size_t)b * 2048 + (size_t)h * 128) * 2048;  // [b][h*128+dh][s]

  // Q fragments (B operand of S^T): lane holds Q[q=lq][dh = kk*32 + g*8 + j]
  bf16x8 qf[4];
  {
    const u16* qp = Q + qk_base + (size_t)(qb * 64 + wave * 16 + lq) * 2048 + g * 8;
#pragma unroll
    for (int kk = 0; kk < 4; ++kk) qf[kk] = *(const bf16x8*)(qp + kk * 32);
  }

  f32x4 acc_o[8];
#pragma unroll
  for (int i = 0; i < 8; ++i) acc_o[i] = f32x4{0.f, 0.f, 0.f, 0.f};
  float l_run = 0.f;

  const int vlr = lane >> 3, vlcs = ((lane & 7) ^ vlr) * 8;

  int kofs[4];
#pragma unroll
  for (int kk = 0; kk < 4; ++kk) kofs[kk] = ((kk * 4 + g) ^ (lq & 7)) * 8;

  // stage K/V tile tt (64 keys) into buf tt&1: 8 gl_lds per thread
  auto stage = [&](int tt) {
    const int buf = tt & 1, kb = tt * 64;
#pragma unroll
    for (int i = 0; i < 4; ++i) {
      const int win = wave * 2 + (i >> 1), half = i & 1;      // wave-uniform
      const int kr = half * 4 + (lane >> 4);                  // row in window
      const int kc = (lane & 15) ^ kr;                        // chunk
      gl_lds16(K + qk_base + (size_t)(kb + win * 8 + kr) * 2048 + kc * 8,
               &Ks[buf][win * 1024 + half * 512]);
      const int vr = wave * 32 + i * 8;                       // wave-uniform
      gl_lds16(Vt + vt_base + (size_t)(vr + vlr) * 2048 + kb + vlcs,
               &Vs[buf][vr * 64]);
    }
  };

  // ---- prologue: publish tile 0 ----
  stage(0);
  asm volatile("s_waitcnt vmcnt(0)" ::: "memory");
  __builtin_amdgcn_s_barrier();
  __builtin_amdgcn_sched_barrier(0);

  for (int tt = 0; tt < 32; ++tt) {
    const int buf = tt & 1;
    if (tt < 31) stage(tt + 1);   // into buf^1: readers done at last barrier

    // S^T tiles: D[key = mt*16 + g*4 + reg][q = lq]
    f32x4 st[4];
#pragma unroll
    for (int mt = 0; mt < 4; ++mt) st[mt] = f32x4{0.f, 0.f, 0.f, 0.f};
#pragma unroll
    for (int kk = 0; kk < 4; ++kk)
#pragma unroll
      for (int mt = 0; mt < 4; ++mt) {
        bf16x8 af = *(const bf16x8*)(&Ks[buf][(mt * 16 + lq) * 128 + kofs[kk]]);
        st[mt] = __builtin_amdgcn_mfma_f32_16x16x32_bf16(af, qf[kk], st[mt], 0, 0, 0);
      }

    // fixed-shift softmax: p = 2^s, packed straight to bf16 pairs in VGPRs
    uint32_t c[4][2];
#pragma unroll
    for (int mt = 0; mt < 4; ++mt) {
      float p0 = fast_exp2(st[mt][0]);
      float p1 = fast_exp2(st[mt][1]);
      float p2 = fast_exp2(st[mt][2]);
      float p3 = fast_exp2(st[mt][3]);
      l_run += (p0 + p1) + (p2 + p3);
      asm("v_cvt_pk_bf16_f32 %0, %1, %2" : "=v"(c[mt][0]) : "v"(p0), "v"(p1));
      asm("v_cvt_pk_bf16_f32 %0, %1, %2" : "=v"(c[mt][1]) : "v"(p2), "v"(p3));
    }

    // PV: O[q][dh] += P[q][key] x V[key][dh]; A-frag built by lane permutes
#pragma unroll
    for (int kk = 0; kk < 2; ++kk) {
      u32x2 s0 = __builtin_amdgcn_permlane32_swap(c[2 * kk][0], c[2 * kk + 1][0], false, false);
      u32x2 r0 = __builtin_amdgcn_permlane16_swap(s0[0], s0[1], false, false);
      u32x2 s1 = __builtin_amdgcn_permlane32_swap(c[2 * kk][1], c[2 * kk + 1][1], false, false);
      u32x2 r1 = __builtin_amdgcn_permlane16_swap(s1[0], s1[1], false, false);
      union { uint32_t d[4]; bf16x8 v; } af;
      af.d[0] = r0[0];   // j=0,1
      af.d[1] = r1[0];   // j=2,3
      af.d[2] = r0[1];   // j=4,5
      af.d[3] = r1[1];   // j=6,7
#pragma unroll
      for (int nt = 0; nt < 8; ++nt) {
        bf16x8 bfr = *(const bf16x8*)(&Vs[buf][(nt * 16 + lq) * 64 + ((kk * 4 + g) ^ (lq & 7)) * 8]);
        acc_o[nt] = __builtin_amdgcn_mfma_f32_16x16x32_bf16(af.v, bfr, acc_o[nt], 0, 0, 0);
      }
    }

    // publish tile tt+1 (stage drained) + release buf[tt&1] for overwrite
    asm volatile("s_waitcnt vmcnt(0)" ::: "memory");
    __builtin_amdgcn_s_barrier();
    __builtin_amdgcn_sched_barrier(0);
  }

  // reduce l across the 4 g-lanes (once), then normalize and store
  l_run += __shfl_xor(l_run, 16);
  l_run += __shfl_xor(l_run, 32);
  const float i0 = 1.f / __shfl(l_run, g * 4 + 0);
  const float i1 = 1.f / __shfl(l_run, g * 4 + 1);
  const float i2 = 1.f / __shfl(l_run, g * 4 + 2);
  const float i3 = 1.f / __shfl(l_run, g * 4 + 3);
  u16* op = O + ((size_t)b * 2048 + qb * 64 + wave * 16) * 2048 + h * 128;
#pragma unroll
  for (int nt = 0; nt < 8; ++nt) {
    op[(size_t)(g * 4 + 0) * 2048 + nt * 16 + lq] = f2bf(acc_o[nt][0] * i0);
    op[(size_t)(g * 4 + 1) * 2048 + nt * 16 + lq] = f2bf(acc_o[nt][1] * i1);
    op[(size_t)(g * 4 + 2) * 2048 + nt * 16 + lq] = f2bf(acc_o[nt][2] * i2);
    op[(size_t)(g * 4 + 3) * 2048 + nt * 16 + lq] = f2bf(acc_o[nt][3] * i3);
  }
}

// ---------------------------------------------------------------------------
extern "C" void kernel_launch(void* const* d_in, const int* in_sizes, int n_in,
                              void* d_out, int out_size, void* d_ws, size_t ws_size,
                              hipStream_t stream) {
  const void* x  = d_in[0];
  const void* Wq = d_in[1];
  const void* Wk = d_in[2];
  const void* Wv = d_in[3];
  const void* Wo = d_in[4];
  u16* ws = (u16*)d_ws;

  const size_t SLOT = 4194304u;  // 2048*2048
  u16* xb  = ws + 0 * SLOT;   // 2 slots (fp32 path only)
  u16* WqT = ws + 2 * SLOT;   // WqT/WkT/WvT contiguous => fused B [6144][2048]
  u16* WoT = ws + 5 * SLOT;
  u16* Qb  = ws + 6 * SLOT;   // attention output aliases this (race-free)
  u16* Kb  = ws + 8 * SLOT;
  u16* Vb  = ws + 10 * SLOT;
  int* flag = (int*)(ws + 12 * SLOT);
  u16* VTd = (u16*)d_out;     // V^T staged in d_out, dead before final GEMM
  u16* Ab  = Qb;

  sniff_k<<<1, 256, 0, stream>>>((const u16*)x, flag);

  convert_x_k<<<4096, 256, 0, stream>>>(x, xb, flag);
  convert_transpose_k<<<dim3(32, 32, 4), 256, 0, stream>>>(Wq, Wk, Wv, Wo, WqT, flag);

  // fused QKV projection (256^2 8-phase, R10 schedule); Q scaled by
  // 128^-0.5 * log2(e)
  const float QSCALE = 0.12751745f;
  gemm256<<<384, 512, 0, stream>>>(xb, x, flag, WqT, Qb, QSCALE);

  transpose_k<<<dim3(32, 32, 2), 256, 0, stream>>>(Vb, VTd);

  attn_kernel<<<dim3(32, 16, 2), dim3(256), 0, stream>>>(Qb, Kb, VTd, Ab);

  gemm_bt<<<dim3(16, 32), 256, 0, stream>>>(Ab, Ab, nullptr, WoT,
                                            (u16*)d_out, (u16*)d_out, (u16*)d_out,
                                            1.0f, flag);
}

// Round 11
// 407.761 us; speedup vs baseline: 1.0317x; 1.0317x over previous
//
#include <hip/hip_runtime.h>
#include <stdint.h>

// ---------------------------------------------------------------------------
// LlamaAttention forward, MI355X (gfx950), input-dtype-agnostic (bf16 or fp32)
//   x:(2,2048,2048) Wq/Wk/Wv/Wo:(2048,2048)  out:(2,2048,2048)
// R16: (1) attn REVERTED to the R7 single-buffer kernel (passed twice,
//   ~130 us; R15's 2-phase double-buffer halved occupancy 4->2 blk/CU and
//   cost +15 us -- inter-block TLP was already hiding the stage latency).
//   (2) gemm256 XCD chunking 2x24 -> 8x6 rectangles: per-XCD panel
//   footprint 26 MB -> 14 MB (LLC->L2 traffic ~1.9x lower). R10/R15
//   counters (MfmaUtil 33, VALU 14, HBM 24%, conflicts 0) point at the
//   LLC serving ~6 TB/s of panel re-reads as the binding resource.
//   gemm256 schedule itself byte-identical to thrice-passed R10.
// Workspace (u16 units, SLOT = 2048*2048 = 4194304):
//   0..1 xb (fp32 path only) | 2..4 WqT WkT WvT (contiguous) | 5 WoT
//   6..7 Q(=Ab) | 8..9 K | 10..11 V | flag at 12*SLOT.  ~96 MB.
//   V^T staged in d_out (dead before final GEMM).
// ---------------------------------------------------------------------------

typedef unsigned short u16;
typedef __attribute__((ext_vector_type(8))) short bf16x8;   // 8 bf16 = 4 VGPRs
typedef __attribute__((ext_vector_type(4))) float f32x4;    // MFMA C/D frag
typedef __attribute__((ext_vector_type(2))) unsigned int u32x2;

__device__ __forceinline__ u16 f2bf(float f) {
  union { float f; uint32_t u; } v; v.f = f;
  return (u16)((v.u + 0x7fffu + ((v.u >> 16) & 1u)) >> 16);  // RNE
}

__device__ __forceinline__ float fast_exp2(float x) {
#if __has_builtin(__builtin_amdgcn_exp2f)
  return __builtin_amdgcn_exp2f(x);
#else
  return exp2f(x);
#endif
}

// async global->LDS, 16 B per lane; lds base must be wave-uniform (m97/m104)
__device__ __forceinline__ void gl_lds16(const void* g, void* l) {
  __builtin_amdgcn_global_load_lds(
      (const __attribute__((address_space(1))) unsigned int*)g,
      (__attribute__((address_space(3))) unsigned int*)l, 16, 0, 0);
}

// ---- dtype sniffer --------------------------------------------------------
__global__ __launch_bounds__(256) void sniff_k(const u16* __restrict__ x,
                                               int* __restrict__ flag) {
  __shared__ int cnt;
  const int t = threadIdx.x;
  if (t == 0) cnt = 0;
  __syncthreads();
  int sane = 0;
#pragma unroll
  for (int i = 0; i < 16; ++i) {
    u16 u = x[t * 16 + i];
    int e = (u >> 7) & 0xff;
    sane += (e >= 90 && e <= 150) ? 1 : 0;
  }
  atomicAdd(&cnt, sane);
  __syncthreads();
  if (t == 0) *flag = (cnt >= 3700) ? 0 : 1;  // 0 = bf16, 1 = fp32
}

// ---- x conversion (fp32 path only; bf16 path early-outs) ------------------
__global__ __launch_bounds__(256) void convert_x_k(const void* __restrict__ xin,
                                                   u16* __restrict__ xb,
                                                   const int* __restrict__ flag) {
  if (*flag == 0) return;  // bf16: GEMM reads x directly
  const int i = (blockIdx.x * 256 + threadIdx.x) * 8;
  const float* xf = (const float*)xin;
  float4 a = *(const float4*)(xf + i);
  float4 b = *(const float4*)(xf + i + 4);
  bf16x8 o;
  o[0] = (short)f2bf(a.x); o[1] = (short)f2bf(a.y);
  o[2] = (short)f2bf(a.z); o[3] = (short)f2bf(a.w);
  o[4] = (short)f2bf(b.x); o[5] = (short)f2bf(b.y);
  o[6] = (short)f2bf(b.z); o[7] = (short)f2bf(b.w);
  *(bf16x8*)(xb + i) = o;
}

// ---- weight convert + transpose, all 4 weights: grid (32,32,4) ------------
__global__ __launch_bounds__(256) void convert_transpose_k(const void* __restrict__ w0,
                                                           const void* __restrict__ w1,
                                                           const void* __restrict__ w2,
                                                           const void* __restrict__ w3,
                                                           u16* __restrict__ out_base,
                                                           const int* __restrict__ flag) {
  __shared__ u16 tile[64][66];
  const int z = blockIdx.z;
  const void* in = (z == 0) ? w0 : (z == 1) ? w1 : (z == 2) ? w2 : w3;
  u16* out = out_base + (size_t)z * 4194304u;
  const int tr = blockIdx.y, tc = blockIdx.x, t = threadIdx.x;
  if (*flag) {
    const float* inf32 = (const float*)in;
#pragma unroll
    for (int i = 0; i < 16; ++i) {
      int idx = t + i * 256, r = idx >> 6, c = idx & 63;
      tile[r][c] = f2bf(inf32[(size_t)(tr * 64 + r) * 2048 + tc * 64 + c]);
    }
  } else {
    const u16* inb = (const u16*)in;
#pragma unroll
    for (int i = 0; i < 16; ++i) {
      int idx = t + i * 256, r = idx >> 6, c = idx & 63;
      tile[r][c] = inb[(size_t)(tr * 64 + r) * 2048 + tc * 64 + c];
    }
  }
  __syncthreads();
#pragma unroll
  for (int i = 0; i < 16; ++i) {
    int idx = t + i * 256, r = idx >> 6, c = idx & 63;
    out[(size_t)(tc * 64 + r) * 2048 + tr * 64 + c] = tile[c][r];
  }
}

// ---- bf16 transpose (V -> V^T per batch), grid (32,32,2) ------------------
__global__ __launch_bounds__(256) void transpose_k(const u16* __restrict__ in,
                                                   u16* __restrict__ out) {
  __shared__ u16 tile[64][66];
  const size_t zoff = (size_t)blockIdx.z * 4194304u;
  in += zoff; out += zoff;
  const int tr = blockIdx.y, tc = blockIdx.x, t = threadIdx.x;
#pragma unroll
  for (int i = 0; i < 16; ++i) {
    int idx = t + i * 256, r = idx >> 6, c = idx & 63;
    tile[r][c] = in[(size_t)(tr * 64 + r) * 2048 + tc * 64 + c];
  }
  __syncthreads();
#pragma unroll
  for (int i = 0; i < 16; ++i) {
    int idx = t + i * 256, r = idx >> 6, c = idx & 63;
    out[(size_t)(tc * 64 + r) * 2048 + tr * 64 + c] = tile[c][r];
  }
}

// ---- 256x256 8-phase GEMM: C = A[4096,2048] x Bt[6144,2048]^T -------------
// R10 schedule (measured 126-128 us, passed 4x). 512 thr = 8 waves. Per phase
// ALL waves compute one 128x128 C-quadrant (mh,nh). Phase reads only A-half
// mh + B-half nh. LDS: Ls[buf][A/B][half][128*64] u16 = 128 KiB.
// Stage schedule (2 gl_lds per half per thread):
//   ph1: u1.HA1+HB1 | ph3: u2.HA0 | ph4: u2.HB0 +vmcnt(4)
//   ph5: u2.HA1+HB1 | ph7: u3.HA0 | ph8: u3.HB0 +vmcnt(4)
// R16: XCD chunking 8bm x 6bn (was 2x24): XCD r = bid&7 covers rect
//   bm in [(r>>2)*8, +8), bn in [(r&3)*6, +6) -> 14 MB panel footprint
//   per XCD (was 26 MB); 6 consecutive j share one A-panel. Bijective.
__global__ __launch_bounds__(512, 2) void gemm256(const u16* __restrict__ A,
                                                  const void* __restrict__ Araw,
                                                  const int* __restrict__ aflag,
                                                  const u16* __restrict__ Bt,
                                                  u16* __restrict__ Cbase,
                                                  float qscale) {
  __shared__ __align__(16) u16 Ls[2][2][2][128 * 64];  // [buf][A/B][half]

  const int t = threadIdx.x, wave = t >> 6, lane = t & 63;
  const int g = lane >> 4, lq = lane & 15;
  const int wr = wave >> 2, wc = wave & 3;   // 2 x 4 wave grid
  // XCD-rect swizzle: 16x24 tile grid partitioned into 8 rects of 8bm x 6bn
  const int bid = blockIdx.x;
  const int r8 = bid & 7, j = bid >> 3;      // XCD id, index within rect
  const int bm = (r8 >> 2) * 8 + j / 6;
  const int bn = (r8 & 3) * 6 + j % 6;

  const u16* Ause = (*aflag == 0) ? (const u16*)Araw : A;
  const u16* Arow = Ause + (size_t)(bm * 256) * 2048;
  const u16* Brow = Bt + (size_t)(bn * 256) * 2048;
  const int lr = lane >> 3, lcs = ((lane & 7) ^ lr) * 8;

  int cofs[2];
#pragma unroll
  for (int kk = 0; kk < 2; ++kk) cofs[kk] = ((kk * 4 + g) ^ (lq & 7)) * 8;

  f32x4 acc[8][4];   // [mh*4+m][nh*2+n]
#pragma unroll
  for (int i = 0; i < 8; ++i)
#pragma unroll
    for (int j2 = 0; j2 < 4; ++j2) acc[i][j2] = f32x4{0.f, 0.f, 0.f, 0.f};

  // stage one half-tile (mat: 0=A 1=B, half h) of K-tile tt into buf tt&1
  auto stageH = [&](int tt, int mat, int h) {
    const u16* src = mat ? Brow : Arow;
    u16* dst = &Ls[tt & 1][mat][h][0];
    const int kb = tt * 64;
#pragma unroll
    for (int i = 0; i < 2; ++i) {
      const int s = wave * 2 + i;    // stripe of 8 rows within the half
      gl_lds16(src + (size_t)(h * 128 + s * 8 + lr) * 2048 + kb + lcs,
               dst + s * 8 * 64);
    }
  };

  bf16x8 af[8], bfr[4];
  auto ldA = [&](const u16* base) {   // base = &Ls[buf][0][mh][0]
#pragma unroll
    for (int m = 0; m < 4; ++m)
#pragma unroll
      for (int kk = 0; kk < 2; ++kk)
        af[m * 2 + kk] = *(const bf16x8*)(&base[(wr * 64 + m * 16 + lq) * 64 + cofs[kk]]);
  };
  auto ldB = [&](const u16* base) {   // base = &Ls[buf][1][nh][0]
#pragma unroll
    for (int n = 0; n < 2; ++n)
#pragma unroll
      for (int kk = 0; kk < 2; ++kk)
        bfr[n * 2 + kk] = *(const bf16x8*)(&base[(wc * 32 + n * 16 + lq) * 64 + cofs[kk]]);
  };
  auto mmac = [&](int mh, int nh) {
    __builtin_amdgcn_s_barrier();
    asm volatile("s_waitcnt lgkmcnt(0)" ::: "memory");
    __builtin_amdgcn_sched_barrier(0);
    __builtin_amdgcn_s_setprio(1);
#pragma unroll
    for (int m = 0; m < 4; ++m)
#pragma unroll
      for (int n = 0; n < 2; ++n)
#pragma unroll
        for (int kk = 0; kk < 2; ++kk)
          acc[mh * 4 + m][nh * 2 + n] = __builtin_amdgcn_mfma_f32_16x16x32_bf16(
              af[m * 2 + kk], bfr[n * 2 + kk], acc[mh * 4 + m][nh * 2 + n], 0, 0, 0);
    __builtin_amdgcn_s_setprio(0);
    __builtin_amdgcn_s_barrier();
  };

  // ---- prologue: tile0 complete + tile1.{HA0,HB0}; retire tile0 ----
  stageH(0, 0, 0); stageH(0, 1, 0); stageH(0, 0, 1); stageH(0, 1, 1);
  stageH(1, 0, 0); stageH(1, 1, 0);
  asm volatile("s_waitcnt vmcnt(4)" ::: "memory");
  __builtin_amdgcn_sched_barrier(0);
  __builtin_amdgcn_s_barrier();

  for (int it = 0; it < 16; ++it) {
    const int u1 = 2 * it + 1, u2 = 2 * it + 2, u3 = 2 * it + 3;
    // ph1: Q(0,0) buf0 | stage u1.HA1 + u1.HB1 (buf1 regions released ph8)
    ldA(&Ls[0][0][0][0]);
    ldB(&Ls[0][1][0][0]);
    stageH(u1, 0, 1); stageH(u1, 1, 1);
    mmac(0, 0);
    // ph2: Q(0,1) buf0 (af reused)
    ldB(&Ls[0][1][1][0]);
    mmac(0, 1);
    // ph3: Q(1,0) buf0 | stage u2.HA0 (buf0.HA0 released ph2)
    ldA(&Ls[0][0][1][0]);
    ldB(&Ls[0][1][0][0]);
    if (u2 < 32) stageH(u2, 0, 0);
    mmac(1, 0);
    // ph4: Q(1,1) buf0 | stage u2.HB0 (released ph3) | vmcnt: publish u1
    ldB(&Ls[0][1][1][0]);
    if (u2 < 32) stageH(u2, 1, 0);
    if (it < 15) asm volatile("s_waitcnt vmcnt(4)" ::: "memory");
    else         asm volatile("s_waitcnt vmcnt(0)" ::: "memory");
    __builtin_amdgcn_sched_barrier(0);
    mmac(1, 1);
    // ph5: Q(0,0) buf1 | stage u2.HA1 + u2.HB1 (buf0 halves released ph4)
    ldA(&Ls[1][0][0][0]);
    ldB(&Ls[1][1][0][0]);
    if (u2 < 32) { stageH(u2, 0, 1); stageH(u2, 1, 1); }
    mmac(0, 0);
    // ph6: Q(0,1) buf1
    ldB(&Ls[1][1][1][0]);
    mmac(0, 1);
    // ph7: Q(1,0) buf1 | stage u3.HA0 (buf1.HA0 released ph6)
    ldA(&Ls[1][0][1][0]);
    ldB(&Ls[1][1][0][0]);
    if (u3 < 32) stageH(u3, 0, 0);
    mmac(1, 0);
    // ph8: Q(1,1) buf1 | stage u3.HB0 (released ph7) | vmcnt: publish u2
    ldB(&Ls[1][1][1][0]);
    if (u3 < 32) stageH(u3, 1, 0);
    asm volatile("s_waitcnt vmcnt(4)" ::: "memory");   // no-op on last iter
    __builtin_amdgcn_sched_barrier(0);
    mmac(1, 1);
  }

  // ---- epilogue: C/D layout col = lane&15, row = (lane>>4)*4 + reg ----
  const int which = bn >> 3;  // 0=Q, 1=K, 2=V (each [4096][2048], contiguous)
  u16* C = Cbase + (size_t)which * 2u * 4194304u;
  const float scale = (which == 0) ? qscale : 1.0f;
  const int colbase = (bn & 7) * 256;
#pragma unroll
  for (int mh = 0; mh < 2; ++mh)
#pragma unroll
    for (int m = 0; m < 4; ++m)
#pragma unroll
      for (int nh = 0; nh < 2; ++nh)
#pragma unroll
        for (int n = 0; n < 2; ++n)
#pragma unroll
          for (int jj = 0; jj < 4; ++jj) {
            size_t row = (size_t)(bm * 256 + mh * 128 + wr * 64 + m * 16 + g * 4 + jj);
            size_t col = (size_t)(colbase + nh * 128 + wc * 32 + n * 16 + lq);
            C[row * 2048 + col] = f2bf(acc[mh * 4 + m][nh * 2 + n][jj] * scale);
          }
}

// ---- C = A[4096,2048] x Bt[*,2048]^T, 128^2 (kept for output GEMM) --------
__global__ __launch_bounds__(256) void gemm_bt(const u16* __restrict__ A,
                                               const void* __restrict__ Araw,
                                               const int* __restrict__ aflag,
                                               const u16* __restrict__ Bt,
                                               u16* __restrict__ C0,
                                               u16* __restrict__ C1,
                                               u16* __restrict__ C2,
                                               float qscale,
                                               const int* __restrict__ outflag) {
  __shared__ u16 As[128 * 64];
  __shared__ u16 Bs[128 * 64];
  const int bx = blockIdx.x, by = blockIdx.y, t = threadIdx.x;
  const int wave = t >> 6, lane = t & 63;
  const int g = lane >> 4, lq = lane & 15;
  const int wr = wave >> 1, wc = wave & 1;
  const int which = bx >> 4, nb = bx & 15;
  u16* C = (which == 0) ? C0 : ((which == 1) ? C1 : C2);
  const float scale = (which == 0) ? qscale : 1.0f;
  const u16* Ause = (aflag && *aflag == 0) ? (const u16*)Araw : A;
  const int lr = lane >> 3, lcs = ((lane & 7) ^ lr) * 8;

  const u16* Arow = Ause + (size_t)(by * 128) * 2048;
  const u16* Brow = Bt + (size_t)(bx * 128) * 2048;

  int cofs[2];
#pragma unroll
  for (int ks = 0; ks < 2; ++ks) cofs[ks] = ((ks * 4 + g) ^ (lq & 7)) * 8;

  f32x4 acc[4][4];
#pragma unroll
  for (int i = 0; i < 4; ++i)
#pragma unroll
    for (int j = 0; j < 4; ++j) acc[i][j] = f32x4{0.f, 0.f, 0.f, 0.f};

  for (int kb = 0; kb < 2048; kb += 64) {
    __syncthreads();
#pragma unroll
    for (int i = 0; i < 4; ++i) {
      const int r = wave * 32 + i * 8;  // wave-uniform LDS base row
      gl_lds16(Arow + (size_t)(r + lr) * 2048 + kb + lcs, &As[r * 64]);
      gl_lds16(Brow + (size_t)(r + lr) * 2048 + kb + lcs, &Bs[r * 64]);
    }
    __syncthreads();
#pragma unroll
    for (int ks = 0; ks < 2; ++ks) {
      bf16x8 af[4], bfr[4];
#pragma unroll
      for (int mt = 0; mt < 4; ++mt)
        af[mt] = *(const bf16x8*)(&As[(wr * 64 + mt * 16 + lq) * 64 + cofs[ks]]);
#pragma unroll
      for (int nt = 0; nt < 4; ++nt)
        bfr[nt] = *(const bf16x8*)(&Bs[(wc * 64 + nt * 16 + lq) * 64 + cofs[ks]]);
#pragma unroll
      for (int mt = 0; mt < 4; ++mt)
#pragma unroll
        for (int nt = 0; nt < 4; ++nt)
          acc[mt][nt] = __builtin_amdgcn_mfma_f32_16x16x32_bf16(af[mt], bfr[nt], acc[mt][nt], 0, 0, 0);
    }
  }
  const int outF32 = outflag ? *outflag : 0;
#pragma unroll
  for (int mt = 0; mt < 4; ++mt)
#pragma unroll
    for (int nt = 0; nt < 4; ++nt)
#pragma unroll
      for (int j = 0; j < 4; ++j) {
        size_t row = (size_t)(by * 128 + wr * 64 + mt * 16 + g * 4 + j);
        size_t col = (size_t)(nb * 128 + wc * 64 + nt * 16 + lq);
        float v = acc[mt][nt][j] * scale;
        if (outF32) ((float*)C)[row * 2048 + col] = v;
        else C[row * 2048 + col] = f2bf(v);
      }
}

// ---- flash attention, fixed-shift softmax, register-resident P ------------
// R16 = R7 kernel (passed twice, ~130 us): single-buffer K/V staging with
// __syncthreads; 4 blk/CU (LDS 32768) -> whole 1024-block grid co-resident;
// inter-block TLP hides the stage latency (double-buffer at 2 blk/CU was
// slower, R15).
__global__ __launch_bounds__(256, 4) void attn_kernel(const u16* __restrict__ Q,
                                                      const u16* __restrict__ K,
                                                      const u16* __restrict__ Vt,
                                                      u16* __restrict__ O) {
  __shared__ u16 Ks[64 * 128];    // chunk (row,c): row*128 + ((c ^ (row&7))*8)
  __shared__ u16 Vs[128 * 64];    // chunk (row,c): row*64  + ((c ^ (row&7))*8)

  const int qb = blockIdx.x, h = blockIdx.y, b = blockIdx.z;
  const int t = threadIdx.x, wave = t >> 6, lane = t & 63;
  const int g = lane >> 4, lq = lane & 15;

  const size_t qk_base = ((size_t)b * 2048) * 2048 + (size_t)h * 128;  // [b][s][h*128+dh]
  const size_t vt_base = ((size_t)b * 2048 + (size_t)h * 128) * 2048;  // [b][h*128+dh][s]

  // Q fragments (B operand of S^T): lane holds Q[q=lq][dh = kk*32 + g*8 + j]
  bf16x8 qf[4];
  {
    const u16* qp = Q + qk_base + (size_t)(qb * 64 + wave * 16 + lq) * 2048 + g * 8;
#pragma unroll
    for (int kk = 0; kk < 4; ++kk) qf[kk] = *(const bf16x8*)(qp + kk * 32);
  }

  f32x4 acc_o[8];
#pragma unroll
  for (int i = 0; i < 8; ++i) acc_o[i] = f32x4{0.f, 0.f, 0.f, 0.f};
  float l_run = 0.f;

  const int vlr = lane >> 3, vlcs = ((lane & 7) ^ vlr) * 8;

  int kofs[4];
#pragma unroll
  for (int kk = 0; kk < 4; ++kk) kofs[kk] = ((kk * 4 + g) ^ (lq & 7)) * 8;

  for (int kb = 0; kb < 2048; kb += 64) {
    __syncthreads();
#pragma unroll
    for (int i = 0; i < 4; ++i) {
      const int win = wave * 2 + (i >> 1), half = i & 1;      // wave-uniform
      const int kr = half * 4 + (lane >> 4);                  // row in window
      const int kc = (lane & 15) ^ kr;                        // chunk
      gl_lds16(K + qk_base + (size_t)(kb + win * 8 + kr) * 2048 + kc * 8,
               &Ks[win * 1024 + half * 512]);
      const int vr = wave * 32 + i * 8;                       // wave-uniform
      gl_lds16(Vt + vt_base + (size_t)(vr + vlr) * 2048 + kb + vlcs,
               &Vs[vr * 64]);
    }
    __syncthreads();

    // S^T tiles: D[key = mt*16 + g*4 + reg][q = lq]
    f32x4 st[4];
#pragma unroll
    for (int mt = 0; mt < 4; ++mt) st[mt] = f32x4{0.f, 0.f, 0.f, 0.f};
#pragma unroll
    for (int kk = 0; kk < 4; ++kk)
#pragma unroll
      for (int mt = 0; mt < 4; ++mt) {
        bf16x8 af = *(const bf16x8*)(&Ks[(mt * 16 + lq) * 128 + kofs[kk]]);
        st[mt] = __builtin_amdgcn_mfma_f32_16x16x32_bf16(af, qf[kk], st[mt], 0, 0, 0);
      }

    // fixed-shift softmax: p = 2^s, packed straight to bf16 pairs in VGPRs
    uint32_t c[4][2];
#pragma unroll
    for (int mt = 0; mt < 4; ++mt) {
      float p0 = fast_exp2(st[mt][0]);
      float p1 = fast_exp2(st[mt][1]);
      float p2 = fast_exp2(st[mt][2]);
      float p3 = fast_exp2(st[mt][3]);
      l_run += (p0 + p1) + (p2 + p3);
      asm("v_cvt_pk_bf16_f32 %0, %1, %2" : "=v"(c[mt][0]) : "v"(p0), "v"(p1));
      asm("v_cvt_pk_bf16_f32 %0, %1, %2" : "=v"(c[mt][1]) : "v"(p2), "v"(p3));
    }

    // PV: O[q][dh] += P[q][key] x V[key][dh]; A-frag built by lane permutes
#pragma unroll
    for (int kk = 0; kk < 2; ++kk) {
      u32x2 s0 = __builtin_amdgcn_permlane32_swap(c[2 * kk][0], c[2 * kk + 1][0], false, false);
      u32x2 r0 = __builtin_amdgcn_permlane16_swap(s0[0], s0[1], false, false);
      u32x2 s1 = __builtin_amdgcn_permlane32_swap(c[2 * kk][1], c[2 * kk + 1][1], false, false);
      u32x2 r1 = __builtin_amdgcn_permlane16_swap(s1[0], s1[1], false, false);
      union { uint32_t d[4]; bf16x8 v; } af;
      af.d[0] = r0[0];   // j=0,1
      af.d[1] = r1[0];   // j=2,3
      af.d[2] = r0[1];   // j=4,5
      af.d[3] = r1[1];   // j=6,7
#pragma unroll
      for (int nt = 0; nt < 8; ++nt) {
        bf16x8 bfr = *(const bf16x8*)(&Vs[(nt * 16 + lq) * 64 + ((kk * 4 + g) ^ (lq & 7)) * 8]);
        acc_o[nt] = __builtin_amdgcn_mfma_f32_16x16x32_bf16(af.v, bfr, acc_o[nt], 0, 0, 0);
      }
    }
  }

  // reduce l across the 4 g-lanes (once), then normalize and store
  l_run += __shfl_xor(l_run, 16);
  l_run += __shfl_xor(l_run, 32);
  const float i0 = 1.f / __shfl(l_run, g * 4 + 0);
  const float i1 = 1.f / __shfl(l_run, g * 4 + 1);
  const float i2 = 1.f / __shfl(l_run, g * 4 + 2);
  const float i3 = 1.f / __shfl(l_run, g * 4 + 3);
  u16* op = O + ((size_t)b * 2048 + qb * 64 + wave * 16) * 2048 + h * 128;
#pragma unroll
  for (int nt = 0; nt < 8; ++nt) {
    op[(size_t)(g * 4 + 0) * 2048 + nt * 16 + lq] = f2bf(acc_o[nt][0] * i0);
    op[(size_t)(g * 4 + 1) * 2048 + nt * 16 + lq] = f2bf(acc_o[nt][1] * i1);
    op[(size_t)(g * 4 + 2) * 2048 + nt * 16 + lq] = f2bf(acc_o[nt][2] * i2);
    op[(size_t)(g * 4 + 3) * 2048 + nt * 16 + lq] = f2bf(acc_o[nt][3] * i3);
  }
}

// ---------------------------------------------------------------------------
extern "C" void kernel_launch(void* const* d_in, const int* in_sizes, int n_in,
                              void* d_out, int out_size, void* d_ws, size_t ws_size,
                              hipStream_t stream) {
  const void* x  = d_in[0];
  const void* Wq = d_in[1];
  const void* Wk = d_in[2];
  const void* Wv = d_in[3];
  const void* Wo = d_in[4];
  u16* ws = (u16*)d_ws;

  const size_t SLOT = 4194304u;  // 2048*2048
  u16* xb  = ws + 0 * SLOT;   // 2 slots (fp32 path only)
  u16* WqT = ws + 2 * SLOT;   // WqT/WkT/WvT contiguous => fused B [6144][2048]
  u16* WoT = ws + 5 * SLOT;
  u16* Qb  = ws + 6 * SLOT;   // attention output aliases this (race-free)
  u16* Kb  = ws + 8 * SLOT;
  u16* Vb  = ws + 10 * SLOT;
  int* flag = (int*)(ws + 12 * SLOT);
  u16* VTd = (u16*)d_out;     // V^T staged in d_out, dead before final GEMM
  u16* Ab  = Qb;

  sniff_k<<<1, 256, 0, stream>>>((const u16*)x, flag);

  convert_x_k<<<4096, 256, 0, stream>>>(x, xb, flag);
  convert_transpose_k<<<dim3(32, 32, 4), 256, 0, stream>>>(Wq, Wk, Wv, Wo, WqT, flag);

  // fused QKV projection (256^2 8-phase, R10 schedule + XCD rects); Q scaled
  // by 128^-0.5 * log2(e)
  const float QSCALE = 0.12751745f;
  gemm256<<<384, 512, 0, stream>>>(xb, x, flag, WqT, Qb, QSCALE);

  transpose_k<<<dim3(32, 32, 2), 256, 0, stream>>>(Vb, VTd);

  attn_kernel<<<dim3(32, 16, 2), dim3(256), 0, stream>>>(Qb, Kb, VTd, Ab);

  gemm_bt<<<dim3(16, 32), 256, 0, stream>>>(Ab, Ab, nullptr, WoT,
                                            (u16*)d_out, (u16*)d_out, (u16*)d_out,
                                            1.0f, flag);
}

// Round 12
// 401.329 us; speedup vs baseline: 1.0482x; 1.0160x over previous
//
#include <hip/hip_runtime.h>
#include <stdint.h>

// ---------------------------------------------------------------------------
// LlamaAttention forward, MI355X (gfx950), input-dtype-agnostic (bf16 or fp32)
//   x:(2,2048,2048) Wq/Wk/Wv/Wo:(2048,2048)  out:(2,2048,2048)
// R17: gemm256 = R10 schedule + R16 XCD-rects + B-REGISTER CACHING ONLY:
//   b0/b1 hold the two B-half fragments across the K-tile, removing the
//   second read of each B-half (ds_read_b128 64 -> 48 per wave per iter,
//   -25% LDS read traffic). R16 showed FETCH halving changes nothing ->
//   not memory-bound below LDS; per-CU LDS reads (512 KiB/iter) exceed
//   MFMA time -> LDS read pipe is the suspected critical path.
//   Barriers, stage placement, vmcnt ledger BYTE-IDENTICAL to 4x-passed
//   R10 (every release now happens earlier -> strictly safer).
//   attn = R7 single-buffer (passed 3x; double-buffer variants regressed
//   or raced, R13-R15).
// Workspace (u16 units, SLOT = 2048*2048 = 4194304):
//   0..1 xb (fp32 path only) | 2..4 WqT WkT WvT (contiguous) | 5 WoT
//   6..7 Q(=Ab) | 8..9 K | 10..11 V | flag at 12*SLOT.  ~96 MB.
//   V^T staged in d_out (dead before final GEMM).
// ---------------------------------------------------------------------------

typedef unsigned short u16;
typedef __attribute__((ext_vector_type(8))) short bf16x8;   // 8 bf16 = 4 VGPRs
typedef __attribute__((ext_vector_type(4))) float f32x4;    // MFMA C/D frag
typedef __attribute__((ext_vector_type(2))) unsigned int u32x2;

__device__ __forceinline__ u16 f2bf(float f) {
  union { float f; uint32_t u; } v; v.f = f;
  return (u16)((v.u + 0x7fffu + ((v.u >> 16) & 1u)) >> 16);  // RNE
}

__device__ __forceinline__ float fast_exp2(float x) {
#if __has_builtin(__builtin_amdgcn_exp2f)
  return __builtin_amdgcn_exp2f(x);
#else
  return exp2f(x);
#endif
}

// async global->LDS, 16 B per lane; lds base must be wave-uniform (m97/m104)
__device__ __forceinline__ void gl_lds16(const void* g, void* l) {
  __builtin_amdgcn_global_load_lds(
      (const __attribute__((address_space(1))) unsigned int*)g,
      (__attribute__((address_space(3))) unsigned int*)l, 16, 0, 0);
}

// ---- dtype sniffer --------------------------------------------------------
__global__ __launch_bounds__(256) void sniff_k(const u16* __restrict__ x,
                                               int* __restrict__ flag) {
  __shared__ int cnt;
  const int t = threadIdx.x;
  if (t == 0) cnt = 0;
  __syncthreads();
  int sane = 0;
#pragma unroll
  for (int i = 0; i < 16; ++i) {
    u16 u = x[t * 16 + i];
    int e = (u >> 7) & 0xff;
    sane += (e >= 90 && e <= 150) ? 1 : 0;
  }
  atomicAdd(&cnt, sane);
  __syncthreads();
  if (t == 0) *flag = (cnt >= 3700) ? 0 : 1;  // 0 = bf16, 1 = fp32
}

// ---- x conversion (fp32 path only; bf16 path early-outs) ------------------
__global__ __launch_bounds__(256) void convert_x_k(const void* __restrict__ xin,
                                                   u16* __restrict__ xb,
                                                   const int* __restrict__ flag) {
  if (*flag == 0) return;  // bf16: GEMM reads x directly
  const int i = (blockIdx.x * 256 + threadIdx.x) * 8;
  const float* xf = (const float*)xin;
  float4 a = *(const float4*)(xf + i);
  float4 b = *(const float4*)(xf + i + 4);
  bf16x8 o;
  o[0] = (short)f2bf(a.x); o[1] = (short)f2bf(a.y);
  o[2] = (short)f2bf(a.z); o[3] = (short)f2bf(a.w);
  o[4] = (short)f2bf(b.x); o[5] = (short)f2bf(b.y);
  o[6] = (short)f2bf(b.z); o[7] = (short)f2bf(b.w);
  *(bf16x8*)(xb + i) = o;
}

// ---- weight convert + transpose, all 4 weights: grid (32,32,4) ------------
__global__ __launch_bounds__(256) void convert_transpose_k(const void* __restrict__ w0,
                                                           const void* __restrict__ w1,
                                                           const void* __restrict__ w2,
                                                           const void* __restrict__ w3,
                                                           u16* __restrict__ out_base,
                                                           const int* __restrict__ flag) {
  __shared__ u16 tile[64][66];
  const int z = blockIdx.z;
  const void* in = (z == 0) ? w0 : (z == 1) ? w1 : (z == 2) ? w2 : w3;
  u16* out = out_base + (size_t)z * 4194304u;
  const int tr = blockIdx.y, tc = blockIdx.x, t = threadIdx.x;
  if (*flag) {
    const float* inf32 = (const float*)in;
#pragma unroll
    for (int i = 0; i < 16; ++i) {
      int idx = t + i * 256, r = idx >> 6, c = idx & 63;
      tile[r][c] = f2bf(inf32[(size_t)(tr * 64 + r) * 2048 + tc * 64 + c]);
    }
  } else {
    const u16* inb = (const u16*)in;
#pragma unroll
    for (int i = 0; i < 16; ++i) {
      int idx = t + i * 256, r = idx >> 6, c = idx & 63;
      tile[r][c] = inb[(size_t)(tr * 64 + r) * 2048 + tc * 64 + c];
    }
  }
  __syncthreads();
#pragma unroll
  for (int i = 0; i < 16; ++i) {
    int idx = t + i * 256, r = idx >> 6, c = idx & 63;
    out[(size_t)(tc * 64 + r) * 2048 + tr * 64 + c] = tile[c][r];
  }
}

// ---- bf16 transpose (V -> V^T per batch), grid (32,32,2) ------------------
__global__ __launch_bounds__(256) void transpose_k(const u16* __restrict__ in,
                                                   u16* __restrict__ out) {
  __shared__ u16 tile[64][66];
  const size_t zoff = (size_t)blockIdx.z * 4194304u;
  in += zoff; out += zoff;
  const int tr = blockIdx.y, tc = blockIdx.x, t = threadIdx.x;
#pragma unroll
  for (int i = 0; i < 16; ++i) {
    int idx = t + i * 256, r = idx >> 6, c = idx & 63;
    tile[r][c] = in[(size_t)(tr * 64 + r) * 2048 + tc * 64 + c];
  }
  __syncthreads();
#pragma unroll
  for (int i = 0; i < 16; ++i) {
    int idx = t + i * 256, r = idx >> 6, c = idx & 63;
    out[(size_t)(tc * 64 + r) * 2048 + tr * 64 + c] = tile[c][r];
  }
}

// ---- 256x256 8-phase GEMM: C = A[4096,2048] x Bt[6144,2048]^T -------------
// R10 schedule + B-reg caching. 512 thr = 8 waves. Per phase ALL waves
// compute one 128x128 C-quadrant (mh,nh). A-half read per mh (ph1/ph3);
// B-halves read ONCE per K-tile into b0/b1 regs (ph1/ph2), reused ph3/ph4.
// LDS: Ls[buf][A/B][half][128*64] u16 = 128 KiB.
// Stage schedule (2 gl_lds per half per thread) -- identical to R10:
//   ph1: u1.HA1+HB1 | ph3: u2.HA0 | ph4: u2.HB0 +vmcnt(4)
//   ph5: u2.HA1+HB1 | ph7: u3.HA0 | ph8: u3.HB0 +vmcnt(4)
// XCD-rect swizzle (R16): 16x24 grid -> 8 rects of 8bm x 6bn. Bijective.
__global__ __launch_bounds__(512, 2) void gemm256(const u16* __restrict__ A,
                                                  const void* __restrict__ Araw,
                                                  const int* __restrict__ aflag,
                                                  const u16* __restrict__ Bt,
                                                  u16* __restrict__ Cbase,
                                                  float qscale) {
  __shared__ __align__(16) u16 Ls[2][2][2][128 * 64];  // [buf][A/B][half]

  const int t = threadIdx.x, wave = t >> 6, lane = t & 63;
  const int g = lane >> 4, lq = lane & 15;
  const int wr = wave >> 2, wc = wave & 3;   // 2 x 4 wave grid
  // XCD-rect swizzle: 16x24 tile grid partitioned into 8 rects of 8bm x 6bn
  const int bid = blockIdx.x;
  const int r8 = bid & 7, j = bid >> 3;      // XCD id, index within rect
  const int bm = (r8 >> 2) * 8 + j / 6;
  const int bn = (r8 & 3) * 6 + j % 6;

  const u16* Ause = (*aflag == 0) ? (const u16*)Araw : A;
  const u16* Arow = Ause + (size_t)(bm * 256) * 2048;
  const u16* Brow = Bt + (size_t)(bn * 256) * 2048;
  const int lr = lane >> 3, lcs = ((lane & 7) ^ lr) * 8;

  int cofs[2];
#pragma unroll
  for (int kk = 0; kk < 2; ++kk) cofs[kk] = ((kk * 4 + g) ^ (lq & 7)) * 8;

  f32x4 acc[8][4];   // [mh*4+m][nh*2+n]
#pragma unroll
  for (int i = 0; i < 8; ++i)
#pragma unroll
    for (int j2 = 0; j2 < 4; ++j2) acc[i][j2] = f32x4{0.f, 0.f, 0.f, 0.f};

  // stage one half-tile (mat: 0=A 1=B, half h) of K-tile tt into buf tt&1
  auto stageH = [&](int tt, int mat, int h) {
    const u16* src = mat ? Brow : Arow;
    u16* dst = &Ls[tt & 1][mat][h][0];
    const int kb = tt * 64;
#pragma unroll
    for (int i = 0; i < 2; ++i) {
      const int s = wave * 2 + i;    // stripe of 8 rows within the half
      gl_lds16(src + (size_t)(h * 128 + s * 8 + lr) * 2048 + kb + lcs,
               dst + s * 8 * 64);
    }
  };

  bf16x8 af[8], b0[4], b1[4];   // A-half frags + B-halves cached per K-tile
  auto ldA = [&](const u16* base) {   // base = &Ls[buf][0][mh][0]
#pragma unroll
    for (int m = 0; m < 4; ++m)
#pragma unroll
      for (int kk = 0; kk < 2; ++kk)
        af[m * 2 + kk] = *(const bf16x8*)(&base[(wr * 64 + m * 16 + lq) * 64 + cofs[kk]]);
  };
  auto ldB = [&](bf16x8* dst, const u16* base) {   // base = &Ls[buf][1][nh][0]
#pragma unroll
    for (int n = 0; n < 2; ++n)
#pragma unroll
      for (int kk = 0; kk < 2; ++kk)
        dst[n * 2 + kk] = *(const bf16x8*)(&base[(wc * 32 + n * 16 + lq) * 64 + cofs[kk]]);
  };
  auto mmac = [&](int mh, int nh, const bf16x8* b) {
    __builtin_amdgcn_s_barrier();
    asm volatile("s_waitcnt lgkmcnt(0)" ::: "memory");
    __builtin_amdgcn_sched_barrier(0);
    __builtin_amdgcn_s_setprio(1);
#pragma unroll
    for (int m = 0; m < 4; ++m)
#pragma unroll
      for (int n = 0; n < 2; ++n)
#pragma unroll
        for (int kk = 0; kk < 2; ++kk)
          acc[mh * 4 + m][nh * 2 + n] = __builtin_amdgcn_mfma_f32_16x16x32_bf16(
              af[m * 2 + kk], b[n * 2 + kk], acc[mh * 4 + m][nh * 2 + n], 0, 0, 0);
    __builtin_amdgcn_s_setprio(0);
    __builtin_amdgcn_s_barrier();
  };

  // ---- prologue: tile0 complete + tile1.{HA0,HB0}; retire tile0 ----
  stageH(0, 0, 0); stageH(0, 1, 0); stageH(0, 0, 1); stageH(0, 1, 1);
  stageH(1, 0, 0); stageH(1, 1, 0);
  asm volatile("s_waitcnt vmcnt(4)" ::: "memory");
  __builtin_amdgcn_sched_barrier(0);
  __builtin_amdgcn_s_barrier();

  for (int it = 0; it < 16; ++it) {
    const int u1 = 2 * it + 1, u2 = 2 * it + 2, u3 = 2 * it + 3;
    // ph1: ldA(mh0)+ldB0 buf0 | stage u1.HA1+HB1 | Q(0,0)
    ldA(&Ls[0][0][0][0]);
    ldB(b0, &Ls[0][1][0][0]);
    stageH(u1, 0, 1); stageH(u1, 1, 1);
    mmac(0, 0, b0);
    // ph2: ldB1 buf0 | Q(0,1)
    ldB(b1, &Ls[0][1][1][0]);
    mmac(0, 1, b1);
    // ph3: ldA(mh1) buf0 | stage u2.HA0 (HA0 last read ph1) | Q(1,0) w/ b0
    ldA(&Ls[0][0][1][0]);
    if (u2 < 32) stageH(u2, 0, 0);
    mmac(1, 0, b0);
    // ph4: no ds reads | stage u2.HB0 (HB0 last read ph1) | vmcnt: publish u1
    if (u2 < 32) stageH(u2, 1, 0);
    if (it < 15) asm volatile("s_waitcnt vmcnt(4)" ::: "memory");
    else         asm volatile("s_waitcnt vmcnt(0)" ::: "memory");
    __builtin_amdgcn_sched_barrier(0);
    mmac(1, 1, b1);
    // ph5: ldA(mh0)+ldB0 buf1 | stage u2.HA1+HB1 | Q(0,0)
    ldA(&Ls[1][0][0][0]);
    ldB(b0, &Ls[1][1][0][0]);
    if (u2 < 32) { stageH(u2, 0, 1); stageH(u2, 1, 1); }
    mmac(0, 0, b0);
    // ph6: ldB1 buf1 | Q(0,1)
    ldB(b1, &Ls[1][1][1][0]);
    mmac(0, 1, b1);
    // ph7: ldA(mh1) buf1 | stage u3.HA0 | Q(1,0) w/ b0
    ldA(&Ls[1][0][1][0]);
    if (u3 < 32) stageH(u3, 0, 0);
    mmac(1, 0, b0);
    // ph8: no ds reads | stage u3.HB0 | vmcnt: publish u2
    if (u3 < 32) stageH(u3, 1, 0);
    asm volatile("s_waitcnt vmcnt(4)" ::: "memory");   // no-op on last iter
    __builtin_amdgcn_sched_barrier(0);
    mmac(1, 1, b1);
  }

  // ---- epilogue: C/D layout col = lane&15, row = (lane>>4)*4 + reg ----
  const int which = bn >> 3;  // 0=Q, 1=K, 2=V (each [4096][2048], contiguous)
  u16* C = Cbase + (size_t)which * 2u * 4194304u;
  const float scale = (which == 0) ? qscale : 1.0f;
  const int colbase = (bn & 7) * 256;
#pragma unroll
  for (int mh = 0; mh < 2; ++mh)
#pragma unroll
    for (int m = 0; m < 4; ++m)
#pragma unroll
      for (int nh = 0; nh < 2; ++nh)
#pragma unroll
        for (int n = 0; n < 2; ++n)
#pragma unroll
          for (int jj = 0; jj < 4; ++jj) {
            size_t row = (size_t)(bm * 256 + mh * 128 + wr * 64 + m * 16 + g * 4 + jj);
            size_t col = (size_t)(colbase + nh * 128 + wc * 32 + n * 16 + lq);
            C[row * 2048 + col] = f2bf(acc[mh * 4 + m][nh * 2 + n][jj] * scale);
          }
}

// ---- C = A[4096,2048] x Bt[*,2048]^T, 128^2 (kept for output GEMM) --------
__global__ __launch_bounds__(256) void gemm_bt(const u16* __restrict__ A,
                                               const void* __restrict__ Araw,
                                               const int* __restrict__ aflag,
                                               const u16* __restrict__ Bt,
                                               u16* __restrict__ C0,
                                               u16* __restrict__ C1,
                                               u16* __restrict__ C2,
                                               float qscale,
                                               const int* __restrict__ outflag) {
  __shared__ u16 As[128 * 64];
  __shared__ u16 Bs[128 * 64];
  const int bx = blockIdx.x, by = blockIdx.y, t = threadIdx.x;
  const int wave = t >> 6, lane = t & 63;
  const int g = lane >> 4, lq = lane & 15;
  const int wr = wave >> 1, wc = wave & 1;
  const int which = bx >> 4, nb = bx & 15;
  u16* C = (which == 0) ? C0 : ((which == 1) ? C1 : C2);
  const float scale = (which == 0) ? qscale : 1.0f;
  const u16* Ause = (aflag && *aflag == 0) ? (const u16*)Araw : A;
  const int lr = lane >> 3, lcs = ((lane & 7) ^ lr) * 8;

  const u16* Arow = Ause + (size_t)(by * 128) * 2048;
  const u16* Brow = Bt + (size_t)(bx * 128) * 2048;

  int cofs[2];
#pragma unroll
  for (int ks = 0; ks < 2; ++ks) cofs[ks] = ((ks * 4 + g) ^ (lq & 7)) * 8;

  f32x4 acc[4][4];
#pragma unroll
  for (int i = 0; i < 4; ++i)
#pragma unroll
    for (int j = 0; j < 4; ++j) acc[i][j] = f32x4{0.f, 0.f, 0.f, 0.f};

  for (int kb = 0; kb < 2048; kb += 64) {
    __syncthreads();
#pragma unroll
    for (int i = 0; i < 4; ++i) {
      const int r = wave * 32 + i * 8;  // wave-uniform LDS base row
      gl_lds16(Arow + (size_t)(r + lr) * 2048 + kb + lcs, &As[r * 64]);
      gl_lds16(Brow + (size_t)(r + lr) * 2048 + kb + lcs, &Bs[r * 64]);
    }
    __syncthreads();
#pragma unroll
    for (int ks = 0; ks < 2; ++ks) {
      bf16x8 af[4], bfr[4];
#pragma unroll
      for (int mt = 0; mt < 4; ++mt)
        af[mt] = *(const bf16x8*)(&As[(wr * 64 + mt * 16 + lq) * 64 + cofs[ks]]);
#pragma unroll
      for (int nt = 0; nt < 4; ++nt)
        bfr[nt] = *(const bf16x8*)(&Bs[(wc * 64 + nt * 16 + lq) * 64 + cofs[ks]]);
#pragma unroll
      for (int mt = 0; mt < 4; ++mt)
#pragma unroll
        for (int nt = 0; nt < 4; ++nt)
          acc[mt][nt] = __builtin_amdgcn_mfma_f32_16x16x32_bf16(af[mt], bfr[nt], acc[mt][nt], 0, 0, 0);
    }
  }
  const int outF32 = outflag ? *outflag : 0;
#pragma unroll
  for (int mt = 0; mt < 4; ++mt)
#pragma unroll
    for (int nt = 0; nt < 4; ++nt)
#pragma unroll
      for (int j = 0; j < 4; ++j) {
        size_t row = (size_t)(by * 128 + wr * 64 + mt * 16 + g * 4 + j);
        size_t col = (size_t)(nb * 128 + wc * 64 + nt * 16 + lq);
        float v = acc[mt][nt][j] * scale;
        if (outF32) ((float*)C)[row * 2048 + col] = v;
        else C[row * 2048 + col] = f2bf(v);
      }
}

// ---- flash attention, fixed-shift softmax, register-resident P ------------
// R7 kernel (passed 3x, ~130 us): single-buffer K/V staging, 4 blk/CU,
// whole 1024-block grid co-resident; inter-block TLP hides stage latency.
__global__ __launch_bounds__(256, 4) void attn_kernel(const u16* __restrict__ Q,
                                                      const u16* __restrict__ K,
                                                      const u16* __restrict__ Vt,
                                                      u16* __restrict__ O) {
  __shared__ u16 Ks[64 * 128];    // chunk (row,c): row*128 + ((c ^ (row&7))*8)
  __shared__ u16 Vs[128 * 64];    // chunk (row,c): row*64  + ((c ^ (row&7))*8)

  const int qb = blockIdx.x, h = blockIdx.y, b = blockIdx.z;
  const int t = threadIdx.x, wave = t >> 6, lane = t & 63;
  const int g = lane >> 4, lq = lane & 15;

  const size_t qk_base = ((size_t)b * 2048) * 2048 + (size_t)h * 128;  // [b][s][h*128+dh]
  const size_t vt_base = ((size_t)b * 2048 + (size_t)h * 128) * 2048;  // [b][h*128+dh][s]

  // Q fragments (B operand of S^T): lane holds Q[q=lq][dh = kk*32 + g*8 + j]
  bf16x8 qf[4];
  {
    const u16* qp = Q + qk_base + (size_t)(qb * 64 + wave * 16 + lq) * 2048 + g * 8;
#pragma unroll
    for (int kk = 0; kk < 4; ++kk) qf[kk] = *(const bf16x8*)(qp + kk * 32);
  }

  f32x4 acc_o[8];
#pragma unroll
  for (int i = 0; i < 8; ++i) acc_o[i] = f32x4{0.f, 0.f, 0.f, 0.f};
  float l_run = 0.f;

  const int vlr = lane >> 3, vlcs = ((lane & 7) ^ vlr) * 8;

  int kofs[4];
#pragma unroll
  for (int kk = 0; kk < 4; ++kk) kofs[kk] = ((kk * 4 + g) ^ (lq & 7)) * 8;

  for (int kb = 0; kb < 2048; kb += 64) {
    __syncthreads();
#pragma unroll
    for (int i = 0; i < 4; ++i) {
      const int win = wave * 2 + (i >> 1), half = i & 1;      // wave-uniform
      const int kr = half * 4 + (lane >> 4);                  // row in window
      const int kc = (lane & 15) ^ kr;                        // chunk
      gl_lds16(K + qk_base + (size_t)(kb + win * 8 + kr) * 2048 + kc * 8,
               &Ks[win * 1024 + half * 512]);
      const int vr = wave * 32 + i * 8;                       // wave-uniform
      gl_lds16(Vt + vt_base + (size_t)(vr + vlr) * 2048 + kb + vlcs,
               &Vs[vr * 64]);
    }
    __syncthreads();

    // S^T tiles: D[key = mt*16 + g*4 + reg][q = lq]
    f32x4 st[4];
#pragma unroll
    for (int mt = 0; mt < 4; ++mt) st[mt] = f32x4{0.f, 0.f, 0.f, 0.f};
#pragma unroll
    for (int kk = 0; kk < 4; ++kk)
#pragma unroll
      for (int mt = 0; mt < 4; ++mt) {
        bf16x8 af = *(const bf16x8*)(&Ks[(mt * 16 + lq) * 128 + kofs[kk]]);
        st[mt] = __builtin_amdgcn_mfma_f32_16x16x32_bf16(af, qf[kk], st[mt], 0, 0, 0);
      }

    // fixed-shift softmax: p = 2^s, packed straight to bf16 pairs in VGPRs
    uint32_t c[4][2];
#pragma unroll
    for (int mt = 0; mt < 4; ++mt) {
      float p0 = fast_exp2(st[mt][0]);
      float p1 = fast_exp2(st[mt][1]);
      float p2 = fast_exp2(st[mt][2]);
      float p3 = fast_exp2(st[mt][3]);
      l_run += (p0 + p1) + (p2 + p3);
      asm("v_cvt_pk_bf16_f32 %0, %1, %2" : "=v"(c[mt][0]) : "v"(p0), "v"(p1));
      asm("v_cvt_pk_bf16_f32 %0, %1, %2" : "=v"(c[mt][1]) : "v"(p2), "v"(p3));
    }

    // PV: O[q][dh] += P[q][key] x V[key][dh]; A-frag built by lane permutes
#pragma unroll
    for (int kk = 0; kk < 2; ++kk) {
      u32x2 s0 = __builtin_amdgcn_permlane32_swap(c[2 * kk][0], c[2 * kk + 1][0], false, false);
      u32x2 r0 = __builtin_amdgcn_permlane16_swap(s0[0], s0[1], false, false);
      u32x2 s1 = __builtin_amdgcn_permlane32_swap(c[2 * kk][1], c[2 * kk + 1][1], false, false);
      u32x2 r1 = __builtin_amdgcn_permlane16_swap(s1[0], s1[1], false, false);
      union { uint32_t d[4]; bf16x8 v; } af;
      af.d[0] = r0[0];   // j=0,1
      af.d[1] = r1[0];   // j=2,3
      af.d[2] = r0[1];   // j=4,5
      af.d[3] = r1[1];   // j=6,7
#pragma unroll
      for (int nt = 0; nt < 8; ++nt) {
        bf16x8 bfr = *(const bf16x8*)(&Vs[(nt * 16 + lq) * 64 + ((kk * 4 + g) ^ (lq & 7)) * 8]);
        acc_o[nt] = __builtin_amdgcn_mfma_f32_16x16x32_bf16(af.v, bfr, acc_o[nt], 0, 0, 0);
      }
    }
  }

  // reduce l across the 4 g-lanes (once), then normalize and store
  l_run += __shfl_xor(l_run, 16);
  l_run += __shfl_xor(l_run, 32);
  const float i0 = 1.f / __shfl(l_run, g * 4 + 0);
  const float i1 = 1.f / __shfl(l_run, g * 4 + 1);
  const float i2 = 1.f / __shfl(l_run, g * 4 + 2);
  const float i3 = 1.f / __shfl(l_run, g * 4 + 3);
  u16* op = O + ((size_t)b * 2048 + qb * 64 + wave * 16) * 2048 + h * 128;
#pragma unroll
  for (int nt = 0; nt < 8; ++nt) {
    op[(size_t)(g * 4 + 0) * 2048 + nt * 16 + lq] = f2bf(acc_o[nt][0] * i0);
    op[(size_t)(g * 4 + 1) * 2048 + nt * 16 + lq] = f2bf(acc_o[nt][1] * i1);
    op[(size_t)(g * 4 + 2) * 2048 + nt * 16 + lq] = f2bf(acc_o[nt][2] * i2);
    op[(size_t)(g * 4 + 3) * 2048 + nt * 16 + lq] = f2bf(acc_o[nt][3] * i3);
  }
}

// ---------------------------------------------------------------------------
extern "C" void kernel_launch(void* const* d_in, const int* in_sizes, int n_in,
                              void* d_out, int out_size, void* d_ws, size_t ws_size,
                              hipStream_t stream) {
  const void* x  = d_in[0];
  const void* Wq = d_in[1];
  const void* Wk = d_in[2];
  const void* Wv = d_in[3];
  const void* Wo = d_in[4];
  u16* ws = (u16*)d_ws;

  const size_t SLOT = 4194304u;  // 2048*2048
  u16* xb  = ws + 0 * SLOT;   // 2 slots (fp32 path only)
  u16* WqT = ws + 2 * SLOT;   // WqT/WkT/WvT contiguous => fused B [6144][2048]
  u16* WoT = ws + 5 * SLOT;
  u16* Qb  = ws + 6 * SLOT;   // attention output aliases this (race-free)
  u16* Kb  = ws + 8 * SLOT;
  u16* Vb  = ws + 10 * SLOT;
  int* flag = (int*)(ws + 12 * SLOT);
  u16* VTd = (u16*)d_out;     // V^T staged in d_out, dead before final GEMM
  u16* Ab  = Qb;

  sniff_k<<<1, 256, 0, stream>>>((const u16*)x, flag);

  convert_x_k<<<4096, 256, 0, stream>>>(x, xb, flag);
  convert_transpose_k<<<dim3(32, 32, 4), 256, 0, stream>>>(Wq, Wk, Wv, Wo, WqT, flag);

  // fused QKV projection (256^2 8-phase, R10 schedule + XCD rects + B-reg
  // cache); Q scaled by 128^-0.5 * log2(e)
  const float QSCALE = 0.12751745f;
  gemm256<<<384, 512, 0, stream>>>(xb, x, flag, WqT, Qb, QSCALE);

  transpose_k<<<dim3(32, 32, 2), 256, 0, stream>>>(Vb, VTd);

  attn_kernel<<<dim3(32, 16, 2), dim3(256), 0, stream>>>(Qb, Kb, VTd, Ab);

  gemm_bt<<<dim3(16, 32), 256, 0, stream>>>(Ab, Ab, nullptr, WoT,
                                            (u16*)d_out, (u16*)d_out, (u16*)d_out,
                                            1.0f, flag);
}